// Round 13
// baseline (1080.964 us; speedup 1.0000x reference)
//
#include <hip/hip_runtime.h>
#include <hip/hip_bf16.h>

#define DIN 256
#define DH  1024
#define DF  512
#define NROWS 65536

// workspace layout (bytes)
#define WS_WTS   0
#define WS_PB    4718592
#define WS_PC    4980736
#define WS_CNT   5242880
#define WS_OFFS  5243904

typedef __attribute__((ext_vector_type(8))) short bf16x8;
typedef __attribute__((ext_vector_type(4))) float f32x4;

__device__ __forceinline__ unsigned short f2b(float f) {
    union { float f; unsigned u; } v; v.f = f;
    unsigned r = v.u + 0x7FFFu + ((v.u >> 16) & 1u);
    return (unsigned short)(r >> 16);
}

__device__ __forceinline__ void gll16(const void* g, void* l) {
    __builtin_amdgcn_global_load_lds(
        (const __attribute__((address_space(1))) void*)g,
        (__attribute__((address_space(3))) void*)l, 16, 0, 0);
}

// dst[n][k] = (bf16) src[k][n] ; src is K x N row-major fp32
__global__ __launch_bounds__(256) void transpose_to_bf16(
        const float* __restrict__ src, unsigned short* __restrict__ dst,
        int K, int N) {
    __shared__ float tile[64][65];
    int k0 = blockIdx.x * 64, n0 = blockIdx.y * 64;
    int t = threadIdx.x;
    for (int i = 0; i < 16; ++i) {
        int idx = t + i * 256;
        int kk = idx >> 6, nn = idx & 63;
        tile[kk][nn] = src[(size_t)(k0 + kk) * N + (n0 + nn)];
    }
    __syncthreads();
    for (int i = 0; i < 16; ++i) {
        int idx = t + i * 256;
        int nn = idx >> 6, kk = idx & 63;
        dst[(size_t)(n0 + nn) * K + (k0 + kk)] = f2b(tile[kk][nn]);
    }
}

__device__ __forceinline__ int row_tag(const float* obs, int row) {
    float c2 = obs[(size_t)row * DIN + 2];
    float c3 = obs[(size_t)row * DIN + 3];
    return (c2 == 1.0f && c3 == 0.0f) ? 1 : 0;
}

__global__ __launch_bounds__(256) void tag_count(const float* __restrict__ obs,
                                                 int* __restrict__ cnt) {
    int t = threadIdx.x;
    int tag = row_tag(obs, blockIdx.x * 256 + t);
    unsigned long long m = __ballot(tag);
    __shared__ int wc[4];
    if ((t & 63) == 0) wc[t >> 6] = __popcll(m);
    __syncthreads();
    if (t == 0) cnt[blockIdx.x] = wc[0] + wc[1] + wc[2] + wc[3];
}

__global__ __launch_bounds__(256) void scan256(const int* __restrict__ cnt,
                                               int* __restrict__ offs) {
    __shared__ int s[256];
    int t = threadIdx.x;
    s[t] = cnt[t];
    __syncthreads();
    for (int d = 1; d < 256; d <<= 1) {
        int v = (t >= d) ? s[t - d] : 0;
        __syncthreads();
        s[t] += v;
        __syncthreads();
    }
    offs[t] = s[t] - cnt[t];
    if (t == 255) offs[256] = s[255];
}

__global__ __launch_bounds__(256) void fill_perm(const float* __restrict__ obs,
                                                 const int* __restrict__ offs,
                                                 int* __restrict__ pb,
                                                 int* __restrict__ pc) {
    int t = threadIdx.x, bid = blockIdx.x;
    int row = bid * 256 + t;
    int tag = row_tag(obs, row);
    unsigned long long m = __ballot(tag);
    __shared__ int wc[4];
    int lane = t & 63, wv = t >> 6;
    if (lane == 0) wc[wv] = __popcll(m);
    __syncthreads();
    int woff = 0;
    for (int i = 0; i < 4; ++i) if (i < wv) woff += wc[i];
    int lb = woff + __popcll(m & ((1ull << lane) - 1ull));
    int base_b = offs[bid];
    if (tag) pb[base_b + lb] = row;
    else     pc[bid * 256 - base_b + (t - lb)] = row;
}

// LDS map (dynamic, 154112 B, 1 block/CU). ALL barriers are __syncthreads
// (full drains — the proven-clean R6 mechanism, 376 us). R13 delta vs R6:
// 256 threads / 4 waves (1 wave/SIMD -> ~512-reg budget). Wave tiles widen:
//   GEMM1: 32 rows x 64 hcols  (48 reads, 64 MFMA per chunk)
//   GEMM2: 128 rows x 32 fcols/quarter; hA[8][2] (64 VGPR) loaded once per
//          chunk, held across all 4 quarters; acc[8][8] = 256 f32.
// Block LDS reads/chunk: 448KB -> 320KB (-29%). All read patterns identical
// in structure to R6's (conflict-proven). Staging divides by 256 threads.
//   ldsX   @ 0      [128][256] bf16 = 64K  persistent, swz (r&7)<<4
//   ldsW1  @ 65536  [64][256]  bf16 = 32K  single-buffered W1 chunk
//   ldsQA  @ 98304  [128][64]  bf16 = 16K  W2 quarter ping
//   ldsQB  @ 114688 [128][64]  bf16 = 16K  W2 quarter pong
//   ldsH   @ 131072 [128][64]  bf16 = 16K
//   ldsB1  @ 147456 float[1024]
//   ldsB2  @ 151552 float[512]
//   ldsPr  @ 153600 int[128]
__global__ __launch_bounds__(256, 1) void fused_mlp(
    const float* __restrict__ obs,
    const unsigned short* __restrict__ wts,
    const int* __restrict__ perm_b, const int* __restrict__ perm_c,
    const int* __restrict__ offs,
    const float* __restrict__ b1_0, const float* __restrict__ b2_0,
    const float* __restrict__ b1_1, const float* __restrict__ b2_1,
    const float* __restrict__ b1_2, const float* __restrict__ b2_2,
    float* __restrict__ out)
{
    extern __shared__ char lds[];
    char* ldsX  = lds;
    char* ldsW1 = lds + 65536;
    char* ldsQA = lds + 98304;
    char* ldsQB = lds + 114688;
    char* ldsH  = lds + 131072;
    float* ldsB1 = (float*)(lds + 147456);
    float* ldsB2 = (float*)(lds + 151552);
    int*  ldsPr  = (int*)(lds + 153600);

    // bijective XCD swizzle: contiguous bid range per XCD
    const int ob = blockIdx.x;
    const int xcd = ob & 7, ii = ob >> 3;
    const int bid = (xcd == 0) ? ii : (129 + (xcd - 1) * 128 + ii);

    int branch, base, cnt;
    const int* perm;
    if (bid < 512) {
        branch = 2; base = bid * 128; cnt = NROWS; perm = nullptr;
    } else {
        int eb = bid - 512;
        int nb = offs[256];
        int nbb = (nb + 127) >> 7;
        int nc = NROWS - nb;
        int ncb = (nc + 127) >> 7;
        if (eb < nbb)            { branch = 0; base = eb * 128;         cnt = nb; perm = perm_b; }
        else if (eb < nbb + ncb) { branch = 1; base = (eb - nbb) * 128; cnt = nc; perm = perm_c; }
        else return;
    }

    const float* b1 = branch == 0 ? b1_0 : (branch == 1 ? b1_1 : b1_2);
    const float* b2 = branch == 0 ? b2_0 : (branch == 1 ? b2_1 : b2_2);
    const char* w1t = (const char*)(wts + (size_t)branch * (DH * DIN));
    const char* w2t = (const char*)(wts + (size_t)3 * DH * DIN + (size_t)branch * (DF * DH));

    const int t = threadIdx.x;
    const int lane = t & 63;
    const int w = t >> 6;                 // wave 0..3
    const int l15 = lane & 15;
    const int g = lane >> 4;

    // ---- prologue: tables + X staging (256-thread splits)
    ldsB1[t] = b1[t];
    ldsB1[t + 256] = b1[t + 256];
    ldsB1[t + 512] = b1[t + 512];
    ldsB1[t + 768] = b1[t + 768];
    ldsB2[t] = b2[t];
    ldsB2[t + 256] = b2[t + 256];
    if (t < 128) {
        int gr = base + t;
        ldsPr[t] = (gr < cnt) ? (perm ? perm[gr] : gr) : -1;
    }
    #pragma unroll
    for (int i = 0; i < 32; ++i) {
        int idx = t + i * 256;            // 8192 float4 slots
        int r = idx >> 6, c4 = idx & 63;
        int gr = base + r;
        int grow = gr < cnt ? gr : cnt - 1;
        if (perm) grow = perm[grow];
        f32x4 v = *(const f32x4*)(obs + (size_t)grow * DIN + c4 * 4);
        ushort4 p4;
        p4.x = f2b(v.x); p4.y = f2b(v.y); p4.z = f2b(v.z); p4.w = f2b(v.w);
        *(ushort4*)(ldsX + r * 512 + ((c4 * 8) ^ ((r & 7) << 4))) = p4;
    }
    // stage W1[0] (only exposed stage; once per block): 2048 slots
    #pragma unroll
    for (int i = 0; i < 8; ++i) {
        int slot = t + i * 256;
        int nl = slot >> 5, boff = (slot & 31) << 4;
        gll16(w1t + (size_t)nl * 512 + (boff ^ ((nl & 7) << 4)), ldsW1 + slot * 16);
    }
    __syncthreads();

    // GEMM1 wave tile: rows w*32 .. +32, hcols 0..64 (all)
    const int ar0 = w * 32 + l15, ar1 = ar0 + 16;
    const int asw0 = (ar0 & 7) << 4, asw1 = (ar1 & 7) << 4;

    // GEMM2: per quarter, wave covers all 128 rows x fcols w*32..+32
    f32x4 acc[8][8];   // [row-frag][q*2+cf] = 256 f32
    #pragma unroll
    for (int a = 0; a < 8; ++a)
        #pragma unroll
        for (int b = 0; b < 8; ++b)
            #pragma unroll
            for (int e = 0; e < 4; ++e) acc[a][b][e] = 0.0f;

    // W2 quarter stage: 16KB = 1024 slots -> 4 gll16/thread
    #define STAGE_Q(buf, q, hc_)                                               \
        {                                                                      \
            _Pragma("unroll")                                                  \
            for (int i = 0; i < 4; ++i) {                                      \
                int slot = t + i * 256;                                        \
                int nl = slot >> 3, boff = (slot & 7) << 4;                    \
                gll16(w2t + (size_t)((q) * 128 + nl) * 2048 + (hc_) * 128      \
                          + (boff ^ ((nl & 7) << 4)),                          \
                      (buf) + slot * 16);                                      \
            }                                                                  \
        }

    // GEMM2 quarter: 2 cf x 2 k2 B-reads (4), each reused across 8 row-frags
    #define QUARTER_MFMA(buf, q)                                               \
        {                                                                      \
            _Pragma("unroll")                                                  \
            for (int k2 = 0; k2 < 2; ++k2)                                     \
                _Pragma("unroll")                                              \
                for (int cf = 0; cf < 2; ++cf) {                               \
                    int fr = w * 32 + cf * 16 + l15;                           \
                    bf16x8 bb = *(const bf16x8*)((buf) + fr * 128 +            \
                                 ((k2 * 64 + g * 16) ^ ((fr & 7) << 4)));      \
                    _Pragma("unroll")                                          \
                    for (int rf = 0; rf < 8; ++rf)                             \
                        acc[rf][(q) * 2 + cf] = __builtin_amdgcn_mfma_f32_16x16x32_bf16( \
                            hA[rf][k2], bb, acc[rf][(q) * 2 + cf], 0, 0, 0);   \
                }                                                              \
        }

    for (int hc = 0; hc < 16; ++hc) {
        // ---- I1: stage q0->QA ; GEMM1 (32 rows x 64 hcols) + bias/relu -> H
        STAGE_Q(ldsQA, 0, hc);
        f32x4 aH[2][4];
        #pragma unroll
        for (int a = 0; a < 2; ++a)
            #pragma unroll
            for (int b = 0; b < 4; ++b)
                #pragma unroll
                for (int e = 0; e < 4; ++e) aH[a][b][e] = 0.0f;
        __builtin_amdgcn_s_setprio(1);
        #pragma unroll
        for (int kk = 0; kk < 8; ++kk) {
            int kb = kk * 64 + g * 16;
            bf16x8 a0 = *(const bf16x8*)(ldsX + ar0 * 512 + (kb ^ asw0));
            bf16x8 a1 = *(const bf16x8*)(ldsX + ar1 * 512 + (kb ^ asw1));
            #pragma unroll
            for (int bct = 0; bct < 4; ++bct) {
                int bn = bct * 16 + l15;
                bf16x8 bf = *(const bf16x8*)(ldsW1 + bn * 512 + (kb ^ ((bn & 7) << 4)));
                aH[0][bct] = __builtin_amdgcn_mfma_f32_16x16x32_bf16(a0, bf, aH[0][bct], 0, 0, 0);
                aH[1][bct] = __builtin_amdgcn_mfma_f32_16x16x32_bf16(a1, bf, aH[1][bct], 0, 0, 0);
            }
        }
        __builtin_amdgcn_s_setprio(0);
        {
            #pragma unroll
            for (int bct = 0; bct < 4; ++bct) {
                float bv = ldsB1[hc * 64 + bct * 16 + l15];
                int col2 = (bct * 16 + l15) * 2;
                #pragma unroll
                for (int art = 0; art < 2; ++art)
                    #pragma unroll
                    for (int r = 0; r < 4; ++r) {
                        int hrow = w * 32 + art * 16 + g * 4 + r;
                        float vv = fmaxf(aH[art][bct][r] + bv, 0.0f);
                        *(unsigned short*)(ldsH + hrow * 128 + (col2 ^ ((hrow & 7) << 4))) = f2b(vv);
                    }
            }
        }
        __syncthreads();   // B1: drains q0; H visible

        // ---- I2: stage q1->QB ; hA loads (held across all 4 quarters) ; GEMM2 q0
        STAGE_Q(ldsQB, 1, hc);
        bf16x8 hA[8][2];
        #pragma unroll
        for (int rf = 0; rf < 8; ++rf)
            #pragma unroll
            for (int k2 = 0; k2 < 2; ++k2) {
                int hr = rf * 16 + l15;
                hA[rf][k2] = *(const bf16x8*)(ldsH + hr * 128 + ((k2 * 64 + g * 16) ^ ((hr & 7) << 4)));
            }
        __builtin_amdgcn_s_setprio(1);
        QUARTER_MFMA(ldsQA, 0);
        __builtin_amdgcn_s_setprio(0);
        __syncthreads();   // B2: drains q1

        // ---- I3: stage q2->QA ; GEMM2 q1 (QB)
        STAGE_Q(ldsQA, 2, hc);
        __builtin_amdgcn_s_setprio(1);
        QUARTER_MFMA(ldsQB, 1);
        __builtin_amdgcn_s_setprio(0);
        __syncthreads();   // B3: drains q2

        // ---- I4: stage q3->QB ; GEMM2 q2 (QA)
        STAGE_Q(ldsQB, 3, hc);
        __builtin_amdgcn_s_setprio(1);
        QUARTER_MFMA(ldsQA, 2);
        __builtin_amdgcn_s_setprio(0);
        __syncthreads();   // B4: drains q3

        // ---- I5: stage W1[hc+1] ; GEMM2 q3 (QB)
        if (hc < 15) {
            int nchunk = hc + 1;
            #pragma unroll
            for (int i = 0; i < 8; ++i) {
                int slot = t + i * 256;
                int nl = slot >> 5, boff = (slot & 31) << 4;
                gll16(w1t + (size_t)(nchunk * 64 + nl) * 512 + (boff ^ ((nl & 7) << 4)),
                      ldsW1 + slot * 16);
            }
        }
        __builtin_amdgcn_s_setprio(1);
        QUARTER_MFMA(ldsQB, 3);
        __builtin_amdgcn_s_setprio(0);
        __syncthreads();   // B5: drains W1[hc+1]
    }

    // ---- epilogue: bias2 + permuted scatter store
    int colq[8]; float b2v[8];
    #pragma unroll
    for (int cc = 0; cc < 8; ++cc) {
        colq[cc] = (cc >> 1) * 128 + w * 32 + (cc & 1) * 16 + l15;
        b2v[cc] = ldsB2[colq[cc]];
    }
    const int cb = (branch == 2) ? DF : 0;
    #pragma unroll
    for (int rf = 0; rf < 8; ++rf)
        #pragma unroll
        for (int r = 0; r < 4; ++r) {
            int row = rf * 16 + g * 4 + r;
            int prow = ldsPr[row];
            if (prow >= 0) {
                float* op = out + (size_t)prow * (2 * DF) + cb;
                #pragma unroll
                for (int cc = 0; cc < 8; ++cc)
                    op[colq[cc]] = acc[rf][cc][r] + b2v[cc];
            }
        }
}

extern "C" void kernel_launch(void* const* d_in, const int* in_sizes, int n_in,
                              void* d_out, int out_size, void* d_ws, size_t ws_size,
                              hipStream_t stream) {
    const float* obs = (const float*)d_in[0];
    const float* W1[3] = {(const float*)d_in[1], (const float*)d_in[5], (const float*)d_in[9]};
    const float* b1[3] = {(const float*)d_in[2], (const float*)d_in[6], (const float*)d_in[10]};
    const float* W2[3] = {(const float*)d_in[3], (const float*)d_in[7], (const float*)d_in[11]};
    const float* b2[3] = {(const float*)d_in[4], (const float*)d_in[8], (const float*)d_in[12]};

    char* ws = (char*)d_ws;
    unsigned short* wts = (unsigned short*)(ws + WS_WTS);
    int* pb   = (int*)(ws + WS_PB);
    int* pc   = (int*)(ws + WS_PC);
    int* cnt  = (int*)(ws + WS_CNT);
    int* offs = (int*)(ws + WS_OFFS);

    for (int br = 0; br < 3; ++br) {
        transpose_to_bf16<<<dim3(DIN / 64, DH / 64), 256, 0, stream>>>(
            W1[br], wts + (size_t)br * DH * DIN, DIN, DH);
        transpose_to_bf16<<<dim3(DH / 64, DF / 64), 256, 0, stream>>>(
            W2[br], wts + (size_t)3 * DH * DIN + (size_t)br * DF * DH, DH, DF);
    }
    tag_count<<<256, 256, 0, stream>>>(obs, cnt);
    scan256<<<1, 256, 0, stream>>>(cnt, offs);
    fill_perm<<<256, 256, 0, stream>>>(obs, offs, pb, pc);

    hipFuncSetAttribute((const void*)fused_mlp,
                        hipFuncAttributeMaxDynamicSharedMemorySize, 154112);
    fused_mlp<<<1025, 256, 154112, stream>>>(obs, wts, pb, pc, offs,
        b1[0], b2[0], b1[1], b2[1], b1[2], b2[2], (float*)d_out);
}

// Round 14
// 341.807 us; speedup vs baseline: 3.1625x; 3.1625x over previous
//
#include <hip/hip_runtime.h>
#include <hip/hip_bf16.h>

#define DIN 256
#define DH  1024
#define DF  512
#define NROWS 65536

// workspace layout (bytes)
#define WS_WTS   0
#define WS_PB    4718592
#define WS_PC    4980736
#define WS_CNT   5242880
#define WS_OFFS  5243904

typedef __attribute__((ext_vector_type(8))) short bf16x8;
typedef __attribute__((ext_vector_type(4))) float f32x4;

__device__ __forceinline__ unsigned short f2b(float f) {
    union { float f; unsigned u; } v; v.f = f;
    unsigned r = v.u + 0x7FFFu + ((v.u >> 16) & 1u);
    return (unsigned short)(r >> 16);
}

__device__ __forceinline__ void gll16(const void* g, void* l) {
    __builtin_amdgcn_global_load_lds(
        (const __attribute__((address_space(1))) void*)g,
        (__attribute__((address_space(3))) void*)l, 16, 0, 0);
}

// counted waits: loop VMEM stream is EXACTLY the 12 gll16/thread per chunk,
// so vmcnt counts are provable (tables/prologue loads force-drained first).
#define BAR_V(N) asm volatile("s_waitcnt vmcnt(" #N ") lgkmcnt(0)\ns_barrier" ::: "memory")
#define DRAIN_VM() asm volatile("s_waitcnt vmcnt(0)" ::: "memory")

// dst[n][k] = (bf16) src[k][n] ; src is K x N row-major fp32
__global__ __launch_bounds__(256) void transpose_to_bf16(
        const float* __restrict__ src, unsigned short* __restrict__ dst,
        int K, int N) {
    __shared__ float tile[64][65];
    int k0 = blockIdx.x * 64, n0 = blockIdx.y * 64;
    int t = threadIdx.x;
    for (int i = 0; i < 16; ++i) {
        int idx = t + i * 256;
        int kk = idx >> 6, nn = idx & 63;
        tile[kk][nn] = src[(size_t)(k0 + kk) * N + (n0 + nn)];
    }
    __syncthreads();
    for (int i = 0; i < 16; ++i) {
        int idx = t + i * 256;
        int nn = idx >> 6, kk = idx & 63;
        dst[(size_t)(n0 + nn) * K + (k0 + kk)] = f2b(tile[kk][nn]);
    }
}

__device__ __forceinline__ int row_tag(const float* obs, int row) {
    float c2 = obs[(size_t)row * DIN + 2];
    float c3 = obs[(size_t)row * DIN + 3];
    return (c2 == 1.0f && c3 == 0.0f) ? 1 : 0;
}

__global__ __launch_bounds__(256) void tag_count(const float* __restrict__ obs,
                                                 int* __restrict__ cnt) {
    int t = threadIdx.x;
    int tag = row_tag(obs, blockIdx.x * 256 + t);
    unsigned long long m = __ballot(tag);
    __shared__ int wc[4];
    if ((t & 63) == 0) wc[t >> 6] = __popcll(m);
    __syncthreads();
    if (t == 0) cnt[blockIdx.x] = wc[0] + wc[1] + wc[2] + wc[3];
}

__global__ __launch_bounds__(256) void scan256(const int* __restrict__ cnt,
                                               int* __restrict__ offs) {
    __shared__ int s[256];
    int t = threadIdx.x;
    s[t] = cnt[t];
    __syncthreads();
    for (int d = 1; d < 256; d <<= 1) {
        int v = (t >= d) ? s[t - d] : 0;
        __syncthreads();
        s[t] += v;
        __syncthreads();
    }
    offs[t] = s[t] - cnt[t];
    if (t == 255) offs[256] = s[255];
}

__global__ __launch_bounds__(256) void fill_perm(const float* __restrict__ obs,
                                                 const int* __restrict__ offs,
                                                 int* __restrict__ pb,
                                                 int* __restrict__ pc) {
    int t = threadIdx.x, bid = blockIdx.x;
    int row = bid * 256 + t;
    int tag = row_tag(obs, row);
    unsigned long long m = __ballot(tag);
    __shared__ int wc[4];
    int lane = t & 63, wv = t >> 6;
    if (lane == 0) wc[wv] = __popcll(m);
    __syncthreads();
    int woff = 0;
    for (int i = 0; i < 4; ++i) if (i < wv) woff += wc[i];
    int lb = woff + __popcll(m & ((1ull << lane) - 1ull));
    int base_b = offs[bid];
    if (tag) pb[base_b + lb] = row;
    else     pc[bid * 256 - base_b + (t - lb)] = row;
}

// LDS map (dynamic, 154112 B, 1 block/CU). R14 delta vs R6 (376 us):
// stage-motion + counted vmcnt waits. Quarter q0 staged in PREVIOUS chunk's
// I5 (2-interval lead); q1 staged I1 (2-interval lead); W1' moved to I4
// (2-interval lead); q2/q3 unchanged (1-interval). Waits retire exactly the
// loads needed, keeping younger prefetches in flight:
//   B1 vmcnt(2) | B2 vmcnt(0) | B3 vmcnt(0) | B4 vmcnt(4) | B5 vmcnt(2)
// Per-buffer WAR audit: QA: w(I5p) r(I2) w(I3) r(I4) w(I5) — barriers between
// each; QB: r(I5p) w(I1) r(I3) w(I4) r(I5); W1: r(I1) w(I4). All separated.
//   ldsX   @ 0      [128][256] bf16 = 64K  persistent, swz (r&7)<<4
//   ldsW1  @ 65536  [64][256]  bf16 = 32K  single-buffered W1 chunk
//   ldsQA  @ 98304  [128][64]  bf16 = 16K  W2 quarter ping
//   ldsQB  @ 114688 [128][64]  bf16 = 16K  W2 quarter pong
//   ldsH   @ 131072 [128][64]  bf16 = 16K
//   ldsB1  @ 147456 float[1024]
//   ldsB2  @ 151552 float[512]
//   ldsPr  @ 153600 int[128]
__global__ __launch_bounds__(512, 2) void fused_mlp(
    const float* __restrict__ obs,
    const unsigned short* __restrict__ wts,
    const int* __restrict__ perm_b, const int* __restrict__ perm_c,
    const int* __restrict__ offs,
    const float* __restrict__ b1_0, const float* __restrict__ b2_0,
    const float* __restrict__ b1_1, const float* __restrict__ b2_1,
    const float* __restrict__ b1_2, const float* __restrict__ b2_2,
    float* __restrict__ out)
{
    extern __shared__ char lds[];
    char* ldsX  = lds;
    char* ldsW1 = lds + 65536;
    char* ldsQA = lds + 98304;
    char* ldsQB = lds + 114688;
    char* ldsH  = lds + 131072;
    float* ldsB1 = (float*)(lds + 147456);
    float* ldsB2 = (float*)(lds + 151552);
    int*  ldsPr  = (int*)(lds + 153600);

    // bijective XCD swizzle: contiguous bid range per XCD
    const int ob = blockIdx.x;
    const int xcd = ob & 7, ii = ob >> 3;
    const int bid = (xcd == 0) ? ii : (129 + (xcd - 1) * 128 + ii);

    int branch, base, cnt;
    const int* perm;
    if (bid < 512) {
        branch = 2; base = bid * 128; cnt = NROWS; perm = nullptr;
    } else {
        int eb = bid - 512;
        int nb = offs[256];
        int nbb = (nb + 127) >> 7;
        int nc = NROWS - nb;
        int ncb = (nc + 127) >> 7;
        if (eb < nbb)            { branch = 0; base = eb * 128;         cnt = nb; perm = perm_b; }
        else if (eb < nbb + ncb) { branch = 1; base = (eb - nbb) * 128; cnt = nc; perm = perm_c; }
        else return;
    }

    const float* b1 = branch == 0 ? b1_0 : (branch == 1 ? b1_1 : b1_2);
    const float* b2 = branch == 0 ? b2_0 : (branch == 1 ? b2_1 : b2_2);
    const char* w1t = (const char*)(wts + (size_t)branch * (DH * DIN));
    const char* w2t = (const char*)(wts + (size_t)3 * DH * DIN + (size_t)branch * (DF * DH));

    const int t = threadIdx.x;
    const int lane = t & 63;
    const int w = t >> 6;
    const int l15 = lane & 15;
    const int g = lane >> 4;

    // ---- prologue: tables + X staging (all non-gll16 VMEM lives here)
    ldsB1[t] = b1[t];
    ldsB1[t + 512] = b1[t + 512];
    ldsB2[t] = b2[t];
    if (t < 128) {
        int gr = base + t;
        ldsPr[t] = (gr < cnt) ? (perm ? perm[gr] : gr) : -1;
    }
    #pragma unroll
    for (int i = 0; i < 16; ++i) {
        int idx = t + i * 512;
        int r = idx >> 6, c4 = idx & 63;
        int gr = base + r;
        int grow = gr < cnt ? gr : cnt - 1;
        if (perm) grow = perm[grow];
        f32x4 v = *(const f32x4*)(obs + (size_t)grow * DIN + c4 * 4);
        ushort4 p4;
        p4.x = f2b(v.x); p4.y = f2b(v.y); p4.z = f2b(v.z); p4.w = f2b(v.w);
        *(ushort4*)(ldsX + r * 512 + ((c4 * 8) ^ ((r & 7) << 4))) = p4;
    }
    DRAIN_VM();   // force-drain obs/table loads so loop vmcnt counts are exact

    // W2 quarter stage helper: quarter q of chunk hc -> buf (2 gll16/thread)
    #define STAGE_Q(buf, q, hc_)                                               \
        {                                                                      \
            _Pragma("unroll")                                                  \
            for (int i = 0; i < 2; ++i) {                                      \
                int slot = t + i * 512;                                        \
                int nl = slot >> 3, boff = (slot & 7) << 4;                    \
                gll16(w2t + (size_t)((q) * 128 + nl) * 2048 + (hc_) * 128      \
                          + (boff ^ ((nl & 7) << 4)),                          \
                      (buf) + slot * 16);                                      \
            }                                                                  \
        }

    #define STAGE_W1(hc_)                                                      \
        {                                                                      \
            _Pragma("unroll")                                                  \
            for (int i = 0; i < 4; ++i) {                                      \
                int slot = t + i * 512;                                        \
                int nl = slot >> 5, boff = (slot & 31) << 4;                   \
                gll16(w1t + (size_t)((hc_) * 64 + nl) * 512 + (boff ^ ((nl & 7) << 4)), \
                      ldsW1 + slot * 16);                                      \
            }                                                                  \
        }

    // prologue prefetch: W1[0] (4 loads), then q0 of chunk 0 (2 loads)
    STAGE_W1(0);
    STAGE_Q(ldsQA, 0, 0);
    BAR_V(2);   // retire W1[0] (oldest 4); q0 stays in flight (lead: prologue+I1)

    // wave roles
    const int rg = w & 3, cg = w >> 2;   // GEMM1: rows rg*32, hcols cg*32
    const int wr = w >> 2, wc = w & 3;   // GEMM2: rows wr*64, fcols wc*32/quarter

    const int ar0 = rg * 32 + l15, ar1 = ar0 + 16;
    const int asw0 = (ar0 & 7) << 4, asw1 = (ar1 & 7) << 4;
    const int bn0 = cg * 32 + l15, bn1 = bn0 + 16;
    const int bsw0 = (bn0 & 7) << 4, bsw1 = (bn1 & 7) << 4;

    f32x4 acc[4][8];
    #pragma unroll
    for (int a = 0; a < 4; ++a)
        #pragma unroll
        for (int b = 0; b < 8; ++b)
            #pragma unroll
            for (int e = 0; e < 4; ++e) acc[a][b][e] = 0.0f;

    #define QUARTER_MFMA(buf, c0)                                              \
        {                                                                      \
            _Pragma("unroll")                                                  \
            for (int k2 = 0; k2 < 2; ++k2)                                     \
                _Pragma("unroll")                                              \
                for (int ct = 0; ct < 2; ++ct) {                               \
                    int fr = wc * 32 + ct * 16 + l15;                          \
                    bf16x8 bb = *(const bf16x8*)((buf) + fr * 128 +            \
                                 ((k2 * 64 + g * 16) ^ ((fr & 7) << 4)));      \
                    _Pragma("unroll")                                          \
                    for (int rt = 0; rt < 4; ++rt)                             \
                        acc[rt][(c0) + ct] = __builtin_amdgcn_mfma_f32_16x16x32_bf16( \
                            hA[rt][k2], bb, acc[rt][(c0) + ct], 0, 0, 0);      \
                }                                                              \
        }

    for (int hc = 0; hc < 16; ++hc) {
        // ---- I1: stage q1->QB (QB free since B5) ; GEMM1 + bias/relu -> H
        STAGE_Q(ldsQB, 1, hc);
        f32x4 aH[2][2];
        #pragma unroll
        for (int a = 0; a < 2; ++a)
            #pragma unroll
            for (int b = 0; b < 2; ++b)
                #pragma unroll
                for (int e = 0; e < 4; ++e) aH[a][b][e] = 0.0f;
        __builtin_amdgcn_s_setprio(1);
        #pragma unroll
        for (int kk = 0; kk < 8; ++kk) {
            int kb = kk * 64 + g * 16;
            bf16x8 a0 = *(const bf16x8*)(ldsX  + ar0 * 512 + (kb ^ asw0));
            bf16x8 a1 = *(const bf16x8*)(ldsX  + ar1 * 512 + (kb ^ asw1));
            bf16x8 b0 = *(const bf16x8*)(ldsW1 + bn0 * 512 + (kb ^ bsw0));
            bf16x8 b1f = *(const bf16x8*)(ldsW1 + bn1 * 512 + (kb ^ bsw1));
            aH[0][0] = __builtin_amdgcn_mfma_f32_16x16x32_bf16(a0, b0,  aH[0][0], 0, 0, 0);
            aH[0][1] = __builtin_amdgcn_mfma_f32_16x16x32_bf16(a0, b1f, aH[0][1], 0, 0, 0);
            aH[1][0] = __builtin_amdgcn_mfma_f32_16x16x32_bf16(a1, b0,  aH[1][0], 0, 0, 0);
            aH[1][1] = __builtin_amdgcn_mfma_f32_16x16x32_bf16(a1, b1f, aH[1][1], 0, 0, 0);
        }
        __builtin_amdgcn_s_setprio(0);
        {
            float b1v0 = ldsB1[hc * 64 + cg * 32 + l15];
            float b1v1 = ldsB1[hc * 64 + cg * 32 + 16 + l15];
            #pragma unroll
            for (int art = 0; art < 2; ++art)
                #pragma unroll
                for (int bct = 0; bct < 2; ++bct) {
                    int col2 = (cg * 32 + bct * 16 + l15) * 2;
                    float bv = bct ? b1v1 : b1v0;
                    #pragma unroll
                    for (int r = 0; r < 4; ++r) {
                        int hrow = rg * 32 + art * 16 + g * 4 + r;
                        float vv = fmaxf(aH[art][bct][r] + bv, 0.0f);
                        *(unsigned short*)(ldsH + hrow * 128 + (col2 ^ ((hrow & 7) << 4))) = f2b(vv);
                    }
                }
        }
        BAR_V(2);   // B1: retire q0 (keep q1); H visible

        // ---- I2: hA loads ; GEMM2 q0 (QA)
        bf16x8 hA[4][2];
        #pragma unroll
        for (int rt = 0; rt < 4; ++rt)
            #pragma unroll
            for (int k2 = 0; k2 < 2; ++k2) {
                int hr = wr * 64 + rt * 16 + l15;
                hA[rt][k2] = *(const bf16x8*)(ldsH + hr * 128 + ((k2 * 64 + g * 16) ^ ((hr & 7) << 4)));
            }
        __builtin_amdgcn_s_setprio(1);
        QUARTER_MFMA(ldsQA, 0);
        __builtin_amdgcn_s_setprio(0);
        BAR_V(0);   // B2: retire q1 (2-interval lead, likely no stall)

        // ---- I3: stage q2->QA (QA free after I2) ; GEMM2 q1 (QB)
        STAGE_Q(ldsQA, 2, hc);
        __builtin_amdgcn_s_setprio(1);
        QUARTER_MFMA(ldsQB, 2);
        __builtin_amdgcn_s_setprio(0);
        BAR_V(0);   // B3: retire q2

        // ---- I4: stage q3->QB ; stage W1[hc+1] ; GEMM2 q2 (QA)
        STAGE_Q(ldsQB, 3, hc);
        STAGE_W1((hc + 1) & 15);   // uniform count (wasted refetch on hc=15)
        __builtin_amdgcn_s_setprio(1);
        QUARTER_MFMA(ldsQA, 4);
        __builtin_amdgcn_s_setprio(0);
        BAR_V(4);   // B4: retire q3 (keep W1')

        // ---- I5: stage next q0->QA (QA free after I4) ; GEMM2 q3 (QB)
        STAGE_Q(ldsQA, 0, (hc + 1) & 15);   // uniform count
        __builtin_amdgcn_s_setprio(1);
        QUARTER_MFMA(ldsQB, 6);
        __builtin_amdgcn_s_setprio(0);
        BAR_V(2);   // B5: retire W1' (keep next q0)
    }
    DRAIN_VM();   // retire dangling hc=15 prefetches before kernel end

    // ---- epilogue: bias2 + permuted scatter store
    int colq[8]; float b2v[8];
    #pragma unroll
    for (int q = 0; q < 8; ++q) {
        colq[q] = (q >> 1) * 128 + wc * 32 + (q & 1) * 16 + l15;
        b2v[q] = ldsB2[colq[q]];
    }
    const int cb = (branch == 2) ? DF : 0;
    #pragma unroll
    for (int rt = 0; rt < 4; ++rt)
        #pragma unroll
        for (int r = 0; r < 4; ++r) {
            int row = wr * 64 + rt * 16 + g * 4 + r;
            int prow = ldsPr[row];
            if (prow >= 0) {
                float* op = out + (size_t)prow * (2 * DF) + cb;
                #pragma unroll
                for (int q = 0; q < 8; ++q)
                    op[colq[q]] = acc[rt][q][r] + b2v[q];
            }
        }
}

extern "C" void kernel_launch(void* const* d_in, const int* in_sizes, int n_in,
                              void* d_out, int out_size, void* d_ws, size_t ws_size,
                              hipStream_t stream) {
    const float* obs = (const float*)d_in[0];
    const float* W1[3] = {(const float*)d_in[1], (const float*)d_in[5], (const float*)d_in[9]};
    const float* b1[3] = {(const float*)d_in[2], (const float*)d_in[6], (const float*)d_in[10]};
    const float* W2[3] = {(const float*)d_in[3], (const float*)d_in[7], (const float*)d_in[11]};
    const float* b2[3] = {(const float*)d_in[4], (const float*)d_in[8], (const float*)d_in[12]};

    char* ws = (char*)d_ws;
    unsigned short* wts = (unsigned short*)(ws + WS_WTS);
    int* pb   = (int*)(ws + WS_PB);
    int* pc   = (int*)(ws + WS_PC);
    int* cnt  = (int*)(ws + WS_CNT);
    int* offs = (int*)(ws + WS_OFFS);

    for (int br = 0; br < 3; ++br) {
        transpose_to_bf16<<<dim3(DIN / 64, DH / 64), 256, 0, stream>>>(
            W1[br], wts + (size_t)br * DH * DIN, DIN, DH);
        transpose_to_bf16<<<dim3(DH / 64, DF / 64), 256, 0, stream>>>(
            W2[br], wts + (size_t)3 * DH * DIN + (size_t)br * DF * DH, DH, DF);
    }
    tag_count<<<256, 256, 0, stream>>>(obs, cnt);
    scan256<<<1, 256, 0, stream>>>(cnt, offs);
    fill_perm<<<256, 256, 0, stream>>>(obs, offs, pb, pc);

    hipFuncSetAttribute((const void*)fused_mlp,
                        hipFuncAttributeMaxDynamicSharedMemorySize, 154112);
    fused_mlp<<<1025, 512, 154112, stream>>>(obs, wts, pb, pc, offs,
        b1[0], b2[0], b1[1], b2[1], b1[2], b2[2], (float*)d_out);
}